// Round 10
// baseline (1417.815 us; speedup 1.0000x reference)
//
#include <hip/hip_runtime.h>
#include <hip/hip_bf16.h>
#include <cstdint>
#include <cstddef>

// ODE: dy/dt = tanh(y@W1+b1)@W2+b2.
// RK4: 7 steps h=0.2 + 1 step h=0.15 -> 32 flow evals; interior outputs via
// cubic Hermite dense output. 2 dispatches per eval:
//  g1_k : 512 blocks x 256 thr. Tile 64x64, 4 waves = 2 K-halves x 2 M-halves
//         (shared B tile) -> 2 blocks/CU = 2 waves/SIMD. Traffic 128 MB.
//  g2c_k: 128 blocks x 512 thr. Tile 64x64, FULL K=4096, 8 waves =
//         4 K-quarters x 2 M-halves; RK4 combine + Hermite fused in epilogue.
//         16 blocks/XCD -> W2-slice L2-resident. Traffic 128 MB.
// K-loop: ring-4 LDS, depth-2 prefetch, counted s_waitcnt vmcnt(8) (never
// drains mid-loop), raw s_barrier 1/iter. LDS K-reduction, then epilogue.

#define GAS __attribute__((address_space(1)))
#define LAS __attribute__((address_space(3)))

typedef __bf16 bf16x8 __attribute__((ext_vector_type(8)));
typedef float  f32x4  __attribute__((ext_vector_type(4)));
typedef unsigned short u16;

struct P {
  const float *x, *W1, *b1, *W2, *b2;
  float* out;
  u16 *W1t, *W2t, *ybf, *ytbf, *Abuf;
  float *y, *k1a, *k1b, *kb2, *kb3, *kb4;
};

__device__ __forceinline__ u16 f2bf(float f) {
  __hip_bfloat16 h = __float2bfloat16(f);
  return __builtin_bit_cast(u16, h);
}

// ---------------- transpose + convert: W[K][N] fp32 -> Wt[N][K] bf16 ----------------
__global__ __launch_bounds__(256) void transpose_bf16(
    const float* __restrict__ W, u16* __restrict__ Wt, int K, int N) {
  __shared__ u16 tile[32][33];
  int kb = blockIdx.x << 5, nb = blockIdx.y << 5;
  int tx = threadIdx.x & 31, ty = threadIdx.x >> 5;  // 32x8
  #pragma unroll
  for (int i = 0; i < 32; i += 8)
    tile[ty + i][tx] = f2bf(W[(size_t)(kb + ty + i) * N + nb + tx]);
  __syncthreads();
  #pragma unroll
  for (int i = 0; i < 32; i += 8)
    Wt[(size_t)(nb + ty + i) * K + kb + tx] = tile[tx][ty + i];
}

// ---------------- init: y=x, ybf=bf16(x), out[0]=x ----------------
__global__ __launch_bounds__(256) void init_state(
    const float* __restrict__ x, float* __restrict__ y,
    u16* __restrict__ ybf, float* __restrict__ out0) {
  int i = blockIdx.x * 256 + threadIdx.x;
  float4 v = reinterpret_cast<const float4*>(x)[i];
  reinterpret_cast<float4*>(y)[i] = v;
  reinterpret_cast<float4*>(out0)[i] = v;
  reinterpret_cast<ushort4*>(ybf)[i] =
      make_ushort4(f2bf(v.x), f2bf(v.y), f2bf(v.z), f2bf(v.w));
}

// ---------------- per-wave staging of one 32x32 bf16 half-tile ----------------
// LDS rows 64 B (BK=32). Swizzle: 16B slot ^= (row>>1)&3 on the GLOBAL source
// (LDS dest linear: wave-uniform base + lane*16), matching the swizzled read.
__device__ __forceinline__ void stage32(
    const u16* __restrict__ src, int ldk, char* dst, int lane) {
  #pragma unroll
  for (int c = 0; c < 2; ++c) {
    int j = c * 64 + lane;
    int row = j >> 2, slot = j & 3;
    int kc = slot ^ ((row >> 1) & 3);
    __builtin_amdgcn_global_load_lds(
        (const GAS void*)(src + (size_t)row * ldk + kc * 8),
        (LAS void*)(dst + j * 16), 16, 0, 0);
  }
}

// swizzled ds_read of one bf16x8 fragment: region-relative row, k-group g
__device__ __forceinline__ bf16x8 frag(const char* base, int row, int g) {
  return *(const bf16x8*)(base + row * 64 + ((g ^ ((row >> 1) & 3)) << 4));
}

// ---------------- shared K-loop: 64(M)x64(N) tile, KG k-groups, NT iters ----------------
// Wave (kg, mh): wave tile 32x64 over K-slice kg. Ring-4 LDS (KG*8KB per ring):
// region layout per (ring, kg): A 4KB (64 rows x 64B) then B 4KB.
// Writer(t+2) vs readers(t-1, t): ring distance >= 2 mod 4 -> race-free.
template<int NT, int KG>
__device__ __forceinline__ void kloop(
    const u16* __restrict__ Asrc, const u16* __restrict__ Bsrc, int ldk,
    char* L, int kg, int mh, int lane, f32x4 acc[2][4]) {
  const int lrow = lane & 15, kgrp = lane >> 4;

#define STG(t)                                                             \
  {                                                                        \
    char* rb = L + (((t) & 3) * KG + kg) * 8192;                           \
    stage32(Asrc + (t) * 32, ldk, rb + mh * 2048, lane);                   \
    stage32(Bsrc + (t) * 32, ldk, rb + 4096 + mh * 2048, lane);            \
  }

  STG(0);
  STG(1);
  for (int t = 0; t < NT; ++t) {
    if (t + 2 < NT) {
      STG(t + 2);  // 4 loads/wave; keep 8 in flight, wait only for tile t
      asm volatile("s_waitcnt vmcnt(8)" ::: "memory");
    } else if (t + 1 < NT) {
      asm volatile("s_waitcnt vmcnt(4)" ::: "memory");
    } else {
      asm volatile("s_waitcnt vmcnt(0)" ::: "memory");
    }
    __builtin_amdgcn_s_barrier();
    __builtin_amdgcn_sched_barrier(0);
    const char* rb = L + ((t & 3) * KG + kg) * 8192;
    bf16x8 af[2], bf[4];
    #pragma unroll
    for (int mi = 0; mi < 2; ++mi)
      af[mi] = frag(rb, mh * 32 + mi * 16 + lrow, kgrp);
    #pragma unroll
    for (int ni = 0; ni < 4; ++ni)
      bf[ni] = frag(rb + 4096, ni * 16 + lrow, kgrp);
    #pragma unroll
    for (int mi = 0; mi < 2; ++mi)
      #pragma unroll
      for (int ni = 0; ni < 4; ++ni)
        acc[mi][ni] = __builtin_amdgcn_mfma_f32_16x16x32_bf16(
            af[mi], bf[ni], acc[mi][ni], 0, 0, 0);
  }
#undef STG
}

// ---------------- GEMM1: Abuf = tanh(state @ W1t^T + b1) ----------------
// 512 blocks x 256 thr; xcd = b&7 owns 8 N-tiles -> W1 slice 1MB L2-resident.
__global__ __launch_bounds__(256) void g1_k(P p, const u16* __restrict__ st) {
  __shared__ __attribute__((aligned(16))) char L[65536];  // 4 rings x 2 kg x 8KB
  const int tid = threadIdx.x, lane = tid & 63, w = tid >> 6;
  const int kh = w >> 1, mh = w & 1;
  const int b = blockIdx.x;
  const int xcd = b & 7, idx = b >> 3;
  const int nt = xcd * 8 + (idx & 7), mt = idx >> 3;  // 64 Nt x 8 Mt
  const int m0 = mt * 64, n0 = nt * 64;
  const int lrow = lane & 15, kgrp = lane >> 4;

  f32x4 acc[2][4];
  #pragma unroll
  for (int mi = 0; mi < 2; ++mi)
    #pragma unroll
    for (int ni = 0; ni < 4; ++ni) acc[mi][ni] = (f32x4){0.f, 0.f, 0.f, 0.f};

  const u16* Asrc = st + (size_t)(m0 + mh * 32) * 1024 + kh * 512;
  const u16* Bsrc = p.W1t + (size_t)(n0 + mh * 32) * 1024 + kh * 512;
  kloop<16, 2>(Asrc, Bsrc, 1024, L, kh, mh, lane, acc);

  // K-half reduction: kh1 -> LDS, kh0 adds + tanh epilogue
  __syncthreads();
  float* sc = (float*)L;
  if (kh == 1) {
    #pragma unroll
    for (int mi = 0; mi < 2; ++mi)
      #pragma unroll
      for (int ni = 0; ni < 4; ++ni)
        #pragma unroll
        for (int r = 0; r < 4; ++r)
          sc[mh * 2048 + (mi * 16 + kgrp * 4 + r) * 64 + ni * 16 + lrow] =
              acc[mi][ni][r];
  }
  __syncthreads();
  if (kh == 0) {
    // C/D layout: col = lane&15, row = (lane>>4)*4 + reg (m89)
    #pragma unroll
    for (int mi = 0; mi < 2; ++mi)
      #pragma unroll
      for (int ni = 0; ni < 4; ++ni) {
        int gcol = n0 + ni * 16 + lrow;
        float bb = p.b1[gcol];
        #pragma unroll
        for (int r = 0; r < 4; ++r) {
          int rr = mi * 16 + kgrp * 4 + r;
          float v = acc[mi][ni][r] + sc[mh * 2048 + rr * 64 + ni * 16 + lrow] + bb;
          p.Abuf[(size_t)(m0 + mh * 32 + rr) * 4096 + gcol] = f2bf(tanhf(v));
        }
      }
  }
}

// ---------------- GEMM2 (full K=4096) + fused RK4 combine + Hermite ----------------
// 128 blocks x 512 thr; xcd = b&7 owns 2 N-tiles -> W2 slice 1MB L2-resident.
__global__ __launch_bounds__(512) void g2c_k(P p, int n, int e) {
  __shared__ __attribute__((aligned(16))) char L[131072];  // 4 rings x 4 kg x 8KB
  const int tid = threadIdx.x, lane = tid & 63, w = tid >> 6;
  const int kq = w >> 1, mh = w & 1;
  const int b = blockIdx.x;
  const int xcd = b & 7, idx = b >> 3;
  const int nt = xcd * 2 + (idx & 1), mt = idx >> 1;  // 16 Nt x 8 Mt
  const int m0 = mt * 64, n0 = nt * 64;
  const int lrow = lane & 15, kgrp = lane >> 4;
  const int MN = 524288;

  f32x4 acc[2][4];
  #pragma unroll
  for (int mi = 0; mi < 2; ++mi)
    #pragma unroll
    for (int ni = 0; ni < 4; ++ni) acc[mi][ni] = (f32x4){0.f, 0.f, 0.f, 0.f};

  const u16* Asrc = p.Abuf + (size_t)(m0 + mh * 32) * 4096 + kq * 1024;
  const u16* Bsrc = p.W2t + (size_t)(n0 + mh * 32) * 4096 + kq * 1024;
  kloop<32, 4>(Asrc, Bsrc, 4096, L, kq, mh, lane, acc);

  // K-quarter reduction: kq 1..3 -> LDS, kq0 adds
  __syncthreads();
  float* sc = (float*)L;
  if (kq > 0) {
    #pragma unroll
    for (int mi = 0; mi < 2; ++mi)
      #pragma unroll
      for (int ni = 0; ni < 4; ++ni)
        #pragma unroll
        for (int r = 0; r < 4; ++r)
          sc[((kq - 1) * 2 + mh) * 2048 + (mi * 16 + kgrp * 4 + r) * 64 +
             ni * 16 + lrow] = acc[mi][ni][r];
  }
  __syncthreads();
  if (kq != 0) return;

  #pragma unroll
  for (int mi = 0; mi < 2; ++mi)
    #pragma unroll
    for (int ni = 0; ni < 4; ++ni)
      #pragma unroll
      for (int r = 0; r < 4; ++r) {
        int rr = (mi * 16 + kgrp * 4 + r) * 64 + ni * 16 + lrow;
        #pragma unroll
        for (int pw = 0; pw < 3; ++pw)
          acc[mi][ni][r] += sc[(pw * 2 + mh) * 2048 + rr];
      }

  // fused RK4 combine + Hermite (identical math to validated R8 epilogue)
  const float h = (n < 7) ? 0.2f : 0.15f;
  const float h6 = h / 6.f;
  const float coef = (e == 3) ? h : h * 0.5f;
  float* k1buf = (n & 1) ? p.k1b : p.k1a;
  const float* k1prev = (n & 1) ? p.k1a : p.k1b;
  float* kbuf = (e == 1) ? k1buf : (e == 2 ? p.kb2 : p.kb3);
  // Hermite coefs (theta=1/4,1/2,3/4 at h=0.2): {y0, f0*h, y1, f1*h}
  const float4 hc0 = {0.84375f, 0.028125f, 0.15625f, -0.009375f};
  const float4 hc1 = {0.5f,     0.025f,    0.5f,     -0.025f};
  const float4 hc2 = {0.15625f, 0.009375f, 0.84375f, -0.028125f};
  const int outIdx = (n < 7) ? 4 * (n + 1) : 31;

  #pragma unroll
  for (int mi = 0; mi < 2; ++mi) {
    #pragma unroll
    for (int ni = 0; ni < 4; ++ni) {
      int gcol = n0 + ni * 16 + lrow;
      float bb = p.b2[gcol];
      #pragma unroll
      for (int r = 0; r < 4; ++r) {
        int grow = m0 + mh * 32 + mi * 16 + kgrp * 4 + r;
        size_t gi = (size_t)grow * 1024 + gcol;
        float F = acc[mi][ni][r] + bb;
        float yv = p.y[gi];
        if (e < 4) {
          kbuf[gi] = F;
          float nv = yv + coef * F;
          p.ytbf[gi] = f2bf(nv);
          if (e == 1 && n >= 1) {  // Hermite dense output for interval n-1
            float yA = p.out[(size_t)(4 * n - 4) * MN + gi];
            float yB = p.out[(size_t)(4 * n) * MN + gi];
            float f0 = k1prev[gi];
            p.out[(size_t)(4 * n - 3) * MN + gi] =
                hc0.x * yA + hc0.y * f0 + hc0.z * yB + hc0.w * F;
            p.out[(size_t)(4 * n - 2) * MN + gi] =
                hc1.x * yA + hc1.y * f0 + hc1.z * yB + hc1.w * F;
            p.out[(size_t)(4 * n - 1) * MN + gi] =
                hc2.x * yA + hc2.y * f0 + hc2.z * yB + hc2.w * F;
          }
        } else {
          if (n == 7) p.kb4[gi] = F;
          float nv = yv + h6 * (k1buf[gi] + 2.f * p.kb2[gi] +
                                2.f * p.kb3[gi] + F);
          p.y[gi] = nv;
          p.out[(size_t)outIdx * MN + gi] = nv;
          p.ybf[gi] = f2bf(nv);
        }
      }
    }
  }
}

// ---------------- tail Hermite: [out28, out31], h=0.15, theta=1/3,2/3 ----------------
__global__ __launch_bounds__(256) void tail_k(P p) {
  const int q = 131072;
  const float4 tc0 = {0.7407407f, 0.0222222f, 0.2592593f, -0.0111111f};
  const float4 tc1 = {0.2592593f, 0.0111111f, 0.7407407f, -0.0222222f};
  int i = blockIdx.x * 256 + threadIdx.x;
  float4* o4 = (float4*)p.out;
  float4 A_ = o4[(size_t)28 * q + i];
  float4 B_ = o4[(size_t)31 * q + i];
  float4 C_ = ((const float4*)p.k1b)[i];  // k1 of step 7
  float4 D_ = ((const float4*)p.kb4)[i];  // k4 of step 7
  float4 o;
  o.x = tc0.x * A_.x + tc0.y * C_.x + tc0.z * B_.x + tc0.w * D_.x;
  o.y = tc0.x * A_.y + tc0.y * C_.y + tc0.z * B_.y + tc0.w * D_.y;
  o.z = tc0.x * A_.z + tc0.y * C_.z + tc0.z * B_.z + tc0.w * D_.z;
  o.w = tc0.x * A_.w + tc0.y * C_.w + tc0.z * B_.w + tc0.w * D_.w;
  o4[(size_t)29 * q + i] = o;
  o.x = tc1.x * A_.x + tc1.y * C_.x + tc1.z * B_.x + tc1.w * D_.x;
  o.y = tc1.x * A_.y + tc1.y * C_.y + tc1.z * B_.y + tc1.w * D_.y;
  o.z = tc1.x * A_.z + tc1.y * C_.z + tc1.z * B_.z + tc1.w * D_.z;
  o.w = tc1.x * A_.w + tc1.y * C_.w + tc1.z * B_.w + tc1.w * D_.w;
  o4[(size_t)30 * q + i] = o;
}

extern "C" void kernel_launch(void* const* d_in, const int* in_sizes, int n_in,
                              void* d_out, int out_size, void* d_ws, size_t ws_size,
                              hipStream_t stream) {
  P p;
  p.x  = (const float*)d_in[0];
  p.W1 = (const float*)d_in[1];
  p.b1 = (const float*)d_in[2];
  p.W2 = (const float*)d_in[3];
  p.b2 = (const float*)d_in[4];
  p.out = (float*)d_out;

  const int Dq = 1024, Hq = 4096;
  const int MN = 512 * 1024;
  char* ws = (char*)d_ws;
  size_t off = 0;
  p.W1t  = (u16*)(ws + off);   off += (size_t)Hq * Dq * 2;   // 8 MB
  p.W2t  = (u16*)(ws + off);   off += (size_t)Dq * Hq * 2;   // 8 MB
  p.y    = (float*)(ws + off); off += (size_t)MN * 4;        // 2 MB
  p.ybf  = (u16*)(ws + off);   off += (size_t)MN * 2;        // 1 MB
  p.ytbf = (u16*)(ws + off);   off += (size_t)MN * 2;        // 1 MB
  p.Abuf = (u16*)(ws + off);   off += (size_t)512 * Hq * 2;  // 4 MB
  p.k1a  = (float*)(ws + off); off += (size_t)MN * 4;
  p.k1b  = (float*)(ws + off); off += (size_t)MN * 4;
  p.kb2  = (float*)(ws + off); off += (size_t)MN * 4;
  p.kb3  = (float*)(ws + off); off += (size_t)MN * 4;
  p.kb4  = (float*)(ws + off); off += (size_t)MN * 4;
  if (ws_size < off) return;

  transpose_bf16<<<dim3(Dq / 32, Hq / 32), 256, 0, stream>>>(p.W1, p.W1t, Dq, Hq);
  transpose_bf16<<<dim3(Hq / 32, Dq / 32), 256, 0, stream>>>(p.W2, p.W2t, Hq, Dq);
  init_state<<<MN / 4 / 256, 256, 0, stream>>>(p.x, p.y, p.ybf, p.out);

  // 8 steps: n=0..6 h=0.2 (-> out[4(n+1)]), n=7 h=0.15 (-> out[31])
  for (int n = 0; n < 8; ++n) {
    for (int e = 1; e <= 4; ++e) {
      g1_k<<<512, 256, 0, stream>>>(p, (e == 1) ? p.ybf : p.ytbf);
      g2c_k<<<128, 512, 0, stream>>>(p, n, e);
    }
  }
  tail_k<<<512, 256, 0, stream>>>(p);
}